// Round 7
// baseline (398.932 us; speedup 1.0000x reference)
//
#include <hip/hip_runtime.h>
#include <math.h>

#define SEQ   2048
#define DM    1024
#define NH    16
#define DK    64
#define MTOT  4096
// q pre-scale: 1/sqrt(64) * log2(e), so softmax runs in exp2 domain
#define QSCALE 0.18033688011112043f

typedef __bf16 bf16x8 __attribute__((ext_vector_type(8)));
typedef float  f32x4  __attribute__((ext_vector_type(4)));
typedef unsigned short u16;
typedef unsigned long long u64;

// RNE float->bf16 (finite inputs)
__device__ __forceinline__ u16 f2bf(float f) {
    unsigned int u = __float_as_uint(f);
    u += 0x7fff + ((u >> 16) & 1);
    return (u16)(u >> 16);
}

// async global->LDS, 16B per lane; LDS dest = base + lane*16 (HW semantics)
__device__ __forceinline__ void async16(const void* g, void* l) {
    __builtin_amdgcn_global_load_lds(
        (const __attribute__((address_space(1))) unsigned int*)(unsigned long long)g,
        (__attribute__((address_space(3))) unsigned int*)(unsigned int)(unsigned long long)l,
        16, 0, 0);
}

// Alias-safe accessors (memcpy => universal aliasing; same ds codegen)
__device__ __forceinline__ bf16x8 ld16(const u16* p) {        // 16B aligned
    bf16x8 v;
    __builtin_memcpy(&v, p, 16);
    return v;
}
__device__ __forceinline__ void st8(u16* p, unsigned int lo, unsigned int hi) {
    u64 q = ((u64)hi << 32) | lo;
    __builtin_memcpy(p, &q, 8);
}

// R8 LDS swizzle: stride-64 rows (no pad), XOR 16B-granule with row&7.
// u16-unit index; bits 3..5 are the granule bits -> bijective per 8-row
// stripe; applied identically on write (st8) and read (ld16).
__device__ __forceinline__ int swz(int row, int col) {
    return (row * 64 + col) ^ ((row & 7) << 3);
}

// ---------------------------------------------------------------------------
// fp32 -> bf16 elementwise (Q, K, V inputs), 8 elems/thread
// ---------------------------------------------------------------------------
__global__ __launch_bounds__(256)
void cvt_in(const float* __restrict__ Q, const float* __restrict__ K,
            const float* __restrict__ V, u16* __restrict__ Qb,
            u16* __restrict__ Kb, u16* __restrict__ Vb)
{
    const float* src; u16* dst;
    if (blockIdx.z == 0)      { src = Q; dst = Qb; }
    else if (blockIdx.z == 1) { src = K; dst = Kb; }
    else                      { src = V; dst = Vb; }
    const size_t i = ((size_t)blockIdx.x * 256 + threadIdx.x) * 8;
    float4 a = *(const float4*)&src[i];
    float4 b = *(const float4*)&src[i + 4];
    uint4 o;
    o.x = (unsigned)f2bf(a.x) | ((unsigned)f2bf(a.y) << 16);
    o.y = (unsigned)f2bf(a.z) | ((unsigned)f2bf(a.w) << 16);
    o.z = (unsigned)f2bf(b.x) | ((unsigned)f2bf(b.y) << 16);
    o.w = (unsigned)f2bf(b.z) | ((unsigned)f2bf(b.w) << 16);
    *(uint4*)&dst[i] = o;
}

// ---------------------------------------------------------------------------
// W [k][n] fp32 -> Wt [n][k] bf16 (64x64 tiles via LDS)
// ---------------------------------------------------------------------------
__global__ __launch_bounds__(256)
void cvt_wt(const float* __restrict__ Wq, const float* __restrict__ Wk,
            const float* __restrict__ Wv, const float* __restrict__ Wo,
            u16* __restrict__ Tq, u16* __restrict__ Tk,
            u16* __restrict__ Tv, u16* __restrict__ To)
{
    const float* W; u16* Wt;
    if (blockIdx.z == 0)      { W = Wq; Wt = Tq; }
    else if (blockIdx.z == 1) { W = Wk; Wt = Tk; }
    else if (blockIdx.z == 2) { W = Wv; Wt = Tv; }
    else                      { W = Wo; Wt = To; }
    __shared__ float Ts[64][65];
    const int t = threadIdx.x;
    const int k0 = blockIdx.x * 64, n0 = blockIdx.y * 64;
#pragma unroll
    for (int p = 0; p < 4; ++p) {
        const int flat = t + p * 256;
        const int r = flat >> 4, c4 = (flat & 15) * 4;
        float4 v = *(const float4*)&W[(size_t)(k0 + r) * DM + n0 + c4];
        Ts[r][c4 + 0] = v.x; Ts[r][c4 + 1] = v.y;
        Ts[r][c4 + 2] = v.z; Ts[r][c4 + 3] = v.w;
    }
    __syncthreads();
#pragma unroll
    for (int p = 0; p < 2; ++p) {
        const int flat = t + p * 256;
        const int n = flat >> 3, kc = (flat & 7) * 8;
        uint4 o;
        o.x = (unsigned)f2bf(Ts[kc + 0][n]) | ((unsigned)f2bf(Ts[kc + 1][n]) << 16);
        o.y = (unsigned)f2bf(Ts[kc + 2][n]) | ((unsigned)f2bf(Ts[kc + 3][n]) << 16);
        o.z = (unsigned)f2bf(Ts[kc + 4][n]) | ((unsigned)f2bf(Ts[kc + 5][n]) << 16);
        o.w = (unsigned)f2bf(Ts[kc + 6][n]) | ((unsigned)f2bf(Ts[kc + 7][n]) << 16);
        *(uint4*)&Wt[(size_t)(n0 + n) * DM + k0 + kc] = o;
    }
}

// ---------------------------------------------------------------------------
// bf16 MFMA GEMM (R5-proven m97 structure): C = A * Wt^T + bias
// 128x128 tile, BK=32, 4 waves 2x2, each wave 4x4 of 16x16x32 MFMA.
// SCATTER=1: bf16 out [bh][s][dk] (with scale); SCATTER=2: bf16 out
// [bh][dk][s] (transposed); SCATTER=0: fp32 out [m][n].
// ---------------------------------------------------------------------------
template <int SCATTER>
__device__ __forceinline__ void gemm_core(const u16* __restrict__ A,
                                          const u16* __restrict__ Wt,
                                          const float* __restrict__ bias,
                                          void* __restrict__ Out, float scale)
{
    __shared__ u16 As[128 * 32];
    __shared__ u16 Bs[128 * 32];

    const int tid = threadIdx.x;
    const int lane = tid & 63;
    const int wv = __builtin_amdgcn_readfirstlane(tid >> 6);
    const int wm = wv >> 1, wn = wv & 1;
    const int lane15 = lane & 15, quad = lane >> 4;
    const int row0 = blockIdx.x * 128, col0 = blockIdx.y * 128;

    const int arow = lane >> 2;          // 0..15
    const int acol = (lane & 3) * 8;     // bf16 col within 32

    f32x4 acc[4][4];
#pragma unroll
    for (int i = 0; i < 4; ++i)
#pragma unroll
        for (int j = 0; j < 4; ++j) acc[i][j] = (f32x4)0.f;

    for (int k0 = 0; k0 < DM; k0 += 32) {
#pragma unroll
        for (int cc = 0; cc < 2; ++cc) {
            const int c = 2 * wv + cc;
            async16(&A[(size_t)(row0 + c * 16 + arow) * DM + k0 + acol],
                    &As[c * 512]);
            async16(&Wt[(size_t)(col0 + c * 16 + arow) * DM + k0 + acol],
                    &Bs[c * 512]);
        }
        __syncthreads();

        bf16x8 af[4];
#pragma unroll
        for (int mi = 0; mi < 4; ++mi)
            af[mi] = ld16(&As[(wm * 64 + mi * 16 + lane15) * 32 + quad * 8]);
#pragma unroll
        for (int ni = 0; ni < 4; ++ni) {
            bf16x8 bfrag = ld16(&Bs[(wn * 64 + ni * 16 + lane15) * 32 + quad * 8]);
#pragma unroll
            for (int mi = 0; mi < 4; ++mi)
                acc[mi][ni] = __builtin_amdgcn_mfma_f32_16x16x32_bf16(
                    af[mi], bfrag, acc[mi][ni], 0, 0, 0);
        }
        __syncthreads();
    }

#pragma unroll
    for (int mi = 0; mi < 4; ++mi) {
        const int mbase = row0 + wm * 64 + mi * 16 + quad * 4;
#pragma unroll
        for (int ni = 0; ni < 4; ++ni) {
            const int n = col0 + wn * 64 + ni * 16 + lane15;
            const float bz = bias[n];
            if (SCATTER == 1) {
                const int h = n >> 6, dk = n & 63;
#pragma unroll
                for (int r = 0; r < 4; ++r) {
                    const int mm = mbase + r;
                    const int b_ = mm >> 11, s = mm & 2047;
                    ((u16*)Out)[(((size_t)(b_ * NH + h)) * SEQ + s) * DK + dk] =
                        f2bf((acc[mi][ni][r] + bz) * scale);
                }
            } else if (SCATTER == 2) {
                const int h = n >> 6, dk = n & 63;
                const int b_ = mbase >> 11, s0 = mbase & 2047;
                u64 q = (u64)f2bf((acc[mi][ni][0] + bz) * scale)
                      | ((u64)f2bf((acc[mi][ni][1] + bz) * scale) << 16)
                      | ((u64)f2bf((acc[mi][ni][2] + bz) * scale) << 32)
                      | ((u64)f2bf((acc[mi][ni][3] + bz) * scale) << 48);
                u16* dst = (u16*)Out +
                    (((size_t)(b_ * NH + h)) * DK + dk) * SEQ + s0;
                __builtin_memcpy(dst, &q, 8);
            } else {
#pragma unroll
                for (int r = 0; r < 4; ++r) {
                    const int mm = mbase + r;
                    ((float*)Out)[(size_t)mm * DM + n] = acc[mi][ni][r] + bz;
                }
            }
        }
    }
}

__global__ __launch_bounds__(256)
void qkv_gemm(const u16* __restrict__ Qb, const u16* __restrict__ Kb,
              const u16* __restrict__ Vb,
              const u16* __restrict__ Tq, const u16* __restrict__ Tk,
              const u16* __restrict__ Tv,
              const float* __restrict__ bq, const float* __restrict__ bk,
              const float* __restrict__ bv,
              u16* __restrict__ qw, u16* __restrict__ kw, u16* __restrict__ vtw)
{
    if (blockIdx.z == 0)      gemm_core<1>(Qb, Tq, bq, qw, QSCALE);
    else if (blockIdx.z == 1) gemm_core<1>(Kb, Tk, bk, kw, 1.0f);
    else                      gemm_core<2>(Vb, Tv, bv, vtw, 1.0f);
}

// ---------------------------------------------------------------------------
// Output GEMM: 128x64 tiles, BK=32 (R5-proven). 512 blocks (2/CU).
// ---------------------------------------------------------------------------
__global__ __launch_bounds__(256)
void out_gemm(const u16* __restrict__ A, const u16* __restrict__ Wt,
              const float* __restrict__ bias, float* __restrict__ Out)
{
    __shared__ u16 As[128 * 32];
    __shared__ u16 Bs[64 * 32];

    const int tid = threadIdx.x;
    const int lane = tid & 63;
    const int wv = __builtin_amdgcn_readfirstlane(tid >> 6);
    const int wm = wv >> 1, wn = wv & 1;
    const int lane15 = lane & 15, quad = lane >> 4;
    const int row0 = blockIdx.x * 128, col0 = blockIdx.y * 64;

    const int arow = lane >> 2;
    const int acol = (lane & 3) * 8;

    f32x4 acc[4][2];
#pragma unroll
    for (int i = 0; i < 4; ++i)
#pragma unroll
        for (int j = 0; j < 2; ++j) acc[i][j] = (f32x4)0.f;

    for (int k0 = 0; k0 < DM; k0 += 32) {
#pragma unroll
        for (int cc = 0; cc < 2; ++cc) {
            const int c = 2 * wv + cc;
            async16(&A[(size_t)(row0 + c * 16 + arow) * DM + k0 + acol],
                    &As[c * 512]);
        }
        async16(&Wt[(size_t)(col0 + wv * 16 + arow) * DM + k0 + acol],
                &Bs[wv * 512]);
        __syncthreads();

        bf16x8 af[4];
#pragma unroll
        for (int mi = 0; mi < 4; ++mi)
            af[mi] = ld16(&As[(wm * 64 + mi * 16 + lane15) * 32 + quad * 8]);
#pragma unroll
        for (int ni = 0; ni < 2; ++ni) {
            bf16x8 bfrag = ld16(&Bs[(wn * 32 + ni * 16 + lane15) * 32 + quad * 8]);
#pragma unroll
            for (int mi = 0; mi < 4; ++mi)
                acc[mi][ni] = __builtin_amdgcn_mfma_f32_16x16x32_bf16(
                    af[mi], bfrag, acc[mi][ni], 0, 0, 0);
        }
        __syncthreads();
    }

#pragma unroll
    for (int mi = 0; mi < 4; ++mi) {
        const int mbase = row0 + wm * 64 + mi * 16 + quad * 4;
#pragma unroll
        for (int ni = 0; ni < 2; ++ni) {
            const int n = col0 + wn * 32 + ni * 16 + lane15;
            const float bz = bias[n];
#pragma unroll
            for (int r = 0; r < 4; ++r)
                Out[(size_t)(mbase + r) * DM + n] = acc[mi][ni][r] + bz;
        }
    }
}

// ---------------------------------------------------------------------------
// Flash attention, bf16 MFMA, linear softmax, split-K over key QUARTERS.
// KEY TRICK: compute S^T = K*Q^T (operands swapped) -> P repacked in-register
// (exp2 + v_perm) into PV A-fragments; V staged in sigma slot order.
// R8 (occupancy II): 4-way key split (512 keys / 8 tiles per block), grid
// 2048 (8 blocks/CU work) + LDS 36864->32768 B via stride-64 + XOR swizzle
// (both-sides, 16B granule) -> 5 blocks/CU resident = 20 waves/CU (was 16,
// measured 31% occ). Double-buffered, ONE barrier per tile, prefetch loads
// at tile start, LDS writes after PV.
// R7: 4 waves x 32 q-rows sharing one K/V tile. R6: s_setprio around MFMA.
// ---------------------------------------------------------------------------
__global__ __launch_bounds__(256, 5)
void attn_mfma(const u16* __restrict__ qw, const u16* __restrict__ kw,
               const u16* __restrict__ vt, u16* __restrict__ opart,
               float* __restrict__ lw)
{
    __shared__ u16 Ks[2][64 * 64];    // [key][d], stride 64, XOR-swizzled
    __shared__ u16 Vts[2][64 * 64];   // [dv][key-slot], sigma order, swizzled

    const int tid = threadIdx.x;
    const int lane = tid & 63;
    const int wv = tid >> 6;                 // 0..3
    const int lane15 = lane & 15, quad = lane >> 4;

    // XCD-swizzled decode: 4 heads per XCD (2 MB K/V resident in L2)
    const int flat = blockIdx.x;             // 0..2047
    const int xcd = flat & 7;
    const int rest = flat >> 3;              // 0..255
    const int bh = xcd * 4 + (rest & 3);     // 0..31
    const int qt = (rest >> 2) & 15;         // 0..15
    const int ks = rest >> 6;                // key quarter 0..3
    const int q0 = qt * 128;
    const int c0beg = ks * 512;
    const size_t base = (size_t)bh * SEQ * DK;

    // Q fragments (B-operand of S^T): wave rows = q0 + wv*32 + mi*16 + lane15
    bf16x8 qb[2][2];
#pragma unroll
    for (int mi = 0; mi < 2; ++mi)
#pragma unroll
        for (int kk = 0; kk < 2; ++kk)
            qb[mi][kk] = ld16(&qw[base +
                (size_t)(q0 + wv * 32 + mi * 16 + lane15) * DK + kk * 32 + quad * 8]);

    f32x4 o_acc[2][4];
    float lpart[2];
#pragma unroll
    for (int mi = 0; mi < 2; ++mi) {
        lpart[mi] = 0.f;
#pragma unroll
        for (int nd = 0; nd < 4; ++nd) o_acc[mi][nd] = (f32x4)0.f;
    }

    // staging map: 256 thr cover 64 rows x 64 cols (four 16-col quarters)
    const int sr = tid >> 2;                 // 0..63
    const int sh = (tid & 3) * 16;           // col quarter base

    // V slot bases for the 2 col-groups (sigma-contiguous 4-key runs)
    int vslot[2];
#pragma unroll
    for (int j = 0; j < 2; ++j) {
        const int c8 = sh + j * 8;
        const int a = c8 >> 4, b = (c8 >> 2) & 3;
        vslot[j] = (a >> 1) * 32 + b * 8 + (a & 1) * 4;
    }

    // stage tile 0 into buffer 0
#pragma unroll
    for (int j = 0; j < 2; ++j) {
        const int c8 = sh + j * 8;
        uint4 kv = *(const uint4*)&kw[base + (size_t)(c0beg + sr) * DK + c8];
        st8(&Ks[0][swz(sr, c8)], kv.x, kv.y);
        st8(&Ks[0][swz(sr, c8 + 4)], kv.z, kv.w);
        uint4 vv = *(const uint4*)&vt[base + (size_t)sr * SEQ + c0beg + c8];
        st8(&Vts[0][swz(sr, vslot[j])], vv.x, vv.y);
        st8(&Vts[0][swz(sr, vslot[j] + 8)], vv.z, vv.w);
    }
    __syncthreads();

    for (int it = 0; it < 8; ++it) {
        const int cur = it & 1;
        const u16* Kc = &Ks[cur][0];
        const u16* Vc = &Vts[cur][0];

        // prefetch next tile into registers
        uint4 kpre[2], vpre[2];
        const bool more = (it < 7);
        if (more) {
            const int cn = c0beg + (it + 1) * 64;
#pragma unroll
            for (int j = 0; j < 2; ++j) {
                const int c8 = sh + j * 8;
                kpre[j] = *(const uint4*)&kw[base + (size_t)(cn + sr) * DK + c8];
                vpre[j] = *(const uint4*)&vt[base + (size_t)sr * SEQ + cn + c8];
            }
        }

        // S^T = K * Q^T : rows = keys (ki), cols = q
        f32x4 sT[2][4];
#pragma unroll
        for (int mi = 0; mi < 2; ++mi)
#pragma unroll
            for (int ki = 0; ki < 4; ++ki) sT[mi][ki] = (f32x4)0.f;
        __builtin_amdgcn_s_setprio(1);
#pragma unroll
        for (int ki = 0; ki < 4; ++ki)
#pragma unroll
            for (int kk = 0; kk < 2; ++kk) {
                bf16x8 ka = ld16(&Kc[swz(ki * 16 + lane15, kk * 32 + quad * 8)]);
#pragma unroll
                for (int mi = 0; mi < 2; ++mi)
                    sT[mi][ki] = __builtin_amdgcn_mfma_f32_16x16x32_bf16(
                        ka, qb[mi][kk], sT[mi][ki], 0, 0, 0);
            }
        __builtin_amdgcn_s_setprio(0);

        // softmax + IN-REGISTER repack to PV A-fragments
        bf16x8 pa[2][2];
#pragma unroll
        for (int mi = 0; mi < 2; ++mi) {
            unsigned int ulo[4], uhi[4];
#pragma unroll
            for (int ki = 0; ki < 4; ++ki) {
                unsigned int u[4];
#pragma unroll
                for (int r = 0; r < 4; ++r) {
                    const float p = __builtin_amdgcn_exp2f(sT[mi][ki][r]);
                    lpart[mi] += p;
                    u[r] = __float_as_uint(p) + 0x8000u;   // half-up round
                }
                ulo[ki] = __builtin_amdgcn_perm(u[1], u[0], 0x07060302u);
                uhi[ki] = __builtin_amdgcn_perm(u[3], u[2], 0x07060302u);
            }
#pragma unroll
            for (int kk = 0; kk < 2; ++kk) {
                union { uint4 u; bf16x8 v; } pk;
                pk.u.x = ulo[2 * kk];     pk.u.y = uhi[2 * kk];
                pk.u.z = ulo[2 * kk + 1]; pk.u.w = uhi[2 * kk + 1];
                pa[mi][kk] = pk.v;
            }
        }

        // PV: O += P * V  (V in sigma slot order matches pa's k-slots)
        __builtin_amdgcn_s_setprio(1);
#pragma unroll
        for (int nd = 0; nd < 4; ++nd)
#pragma unroll
            for (int kk = 0; kk < 2; ++kk) {
                bf16x8 vb = ld16(&Vc[swz(nd * 16 + lane15, kk * 32 + quad * 8)]);
#pragma unroll
                for (int mi = 0; mi < 2; ++mi)
                    o_acc[mi][nd] = __builtin_amdgcn_mfma_f32_16x16x32_bf16(
                        pa[mi][kk], vb, o_acc[mi][nd], 0, 0, 0);
            }
        __builtin_amdgcn_s_setprio(0);

        // write prefetched tile into the other buffer (its readers finished
        // at the previous barrier), then one barrier to publish + retire cur
        if (more) {
            const int nxt = cur ^ 1;
#pragma unroll
            for (int j = 0; j < 2; ++j) {
                const int c8 = sh + j * 8;
                st8(&Ks[nxt][swz(sr, c8)], kpre[j].x, kpre[j].y);
                st8(&Ks[nxt][swz(sr, c8 + 4)], kpre[j].z, kpre[j].w);
                st8(&Vts[nxt][swz(sr, vslot[j])], vpre[j].x, vpre[j].y);
                st8(&Vts[nxt][swz(sr, vslot[j] + 8)], vpre[j].z, vpre[j].w);
            }
        }
        __syncthreads();
    }

    // epilogue: l lives per-lane at q = mi*16 + lane15; complete across quads
    const size_t rowbase = (size_t)(ks * 32 + bh) * SEQ;
#pragma unroll
    for (int mi = 0; mi < 2; ++mi) {
        float l = lpart[mi];
        l += __shfl_xor(l, 16);
        l += __shfl_xor(l, 32);
        if (quad == 0)
            lw[rowbase + q0 + wv * 32 + mi * 16 + lane15] = l;
    }
    // unnormalized partial O: q = mi*16 + quad*4 + r, dv = nd*16 + lane15
#pragma unroll
    for (int mi = 0; mi < 2; ++mi)
#pragma unroll
        for (int r = 0; r < 4; ++r) {
            const int s = q0 + wv * 32 + mi * 16 + quad * 4 + r;
#pragma unroll
            for (int nd = 0; nd < 4; ++nd)
                opart[(rowbase + s) * DK + nd * 16 + lane15] = f2bf(o_acc[mi][nd][r]);
        }
}

// ---------------------------------------------------------------------------
// Combine the four key-quarter partials: O = (SUM Oi) / (SUM li), bf16 out.
// ---------------------------------------------------------------------------
__global__ __launch_bounds__(256)
void attn_combine(const u16* __restrict__ opart, const float* __restrict__ lw,
                  u16* __restrict__ attnb)
{
    const int flat = blockIdx.x * 256 + threadIdx.x;   // < 524288
    const int dv = (flat & 7) * 8;
    const int s  = (flat >> 3) & 2047;
    const int bh = flat >> 14;
    const size_t stride = (size_t)32 * SEQ * DK;
    const size_t i0 = ((size_t)bh * SEQ + s) * DK + dv;

    float l = 0.f;
#pragma unroll
    for (int p = 0; p < 4; ++p)
        l += lw[(size_t)(p * 32 + bh) * SEQ + s];
    const float inv = 1.f / l;

    float e[8];
#pragma unroll
    for (int j = 0; j < 8; ++j) e[j] = 0.f;
#pragma unroll
    for (int p = 0; p < 4; ++p) {
        uint4 a = *(const uint4*)&opart[i0 + p * stride];
        unsigned int au[4] = {a.x, a.y, a.z, a.w};
#pragma unroll
        for (int j = 0; j < 4; ++j) {
            e[2 * j]     += __uint_as_float(au[j] << 16);
            e[2 * j + 1] += __uint_as_float(au[j] & 0xffff0000u);
        }
    }
    unsigned int ou[4];
#pragma unroll
    for (int j = 0; j < 4; ++j)
        ou[j] = (unsigned)f2bf(e[2 * j] * inv) |
                ((unsigned)f2bf(e[2 * j + 1] * inv) << 16);

    const int b_ = bh >> 4, h = bh & 15;
    uint4 o; o.x = ou[0]; o.y = ou[1]; o.z = ou[2]; o.w = ou[3];
    *(uint4*)&attnb[((size_t)b_ * SEQ + s) * DM + h * DK + dv] = o;
}

// ---------------------------------------------------------------------------
extern "C" void kernel_launch(void* const* d_in, const int* in_sizes, int n_in,
                              void* d_out, int out_size, void* d_ws, size_t ws_size,
                              hipStream_t stream)
{
    const float* Q  = (const float*)d_in[0];
    const float* K  = (const float*)d_in[1];
    const float* V  = (const float*)d_in[2];
    const float* Wq = (const float*)d_in[3];
    const float* bq = (const float*)d_in[4];
    const float* Wk = (const float*)d_in[5];
    const float* bk = (const float*)d_in[6];
    const float* Wv = (const float*)d_in[7];
    const float* bv = (const float*)d_in[8];
    const float* Wo = (const float*)d_in[9];
    const float* bo = (const float*)d_in[10];
    float* out = (float*)d_out;

    // R8 workspace map (peak 59 MB):
    //   0-8   Qbf   (cvt_in -> qkv)        | opart ks0 during attn
    //   8-16  Kbf   (cvt_in -> qkv)        | opart ks1
    //   16-24 Vbf   (cvt_in -> qkv)        | opart ks2
    //   24-30 Wtq/Wtk/Wtv (cvt_wt -> qkv)  | opart ks3 (24-32)
    //   30-32 (free)                       |
    //   32-40 qw    (qkv -> attn)          | attnb (combine -> out_gemm)
    //   40-48 kw    (qkv -> attn)
    //   48-56 vtw   (qkv -> attn)
    //   56-57 lw    (attn -> combine, 1 MB)
    //   57-59 Wto   (cvt_wt -> out_gemm)
    const size_t MB = 1024 * 1024;
    char* w8 = (char*)d_ws;
    u16* Qbf = (u16*)(w8 + 0 * MB);
    u16* Kbf = (u16*)(w8 + 8 * MB);
    u16* Vbf = (u16*)(w8 + 16 * MB);
    u16* Wtq = (u16*)(w8 + 24 * MB);
    u16* Wtk = (u16*)(w8 + 26 * MB);
    u16* Wtv = (u16*)(w8 + 28 * MB);
    u16* qw  = (u16*)(w8 + 32 * MB);
    u16* kw  = (u16*)(w8 + 40 * MB);
    u16* vtw = (u16*)(w8 + 48 * MB);
    float* lwb = (float*)(w8 + 56 * MB); // 1 MB (4 splits)
    u16* Wto = (u16*)(w8 + 57 * MB);     // 2 MB
    u16* opart = Qbf;                    // 32 MB @ 0..32 (4 bf16 partials)
    u16* attnb = qw;                     // alias: qw dead after attn_mfma

    cvt_in<<<dim3(2048, 1, 3), 256, 0, stream>>>(Q, K, V, Qbf, Kbf, Vbf);
    cvt_wt<<<dim3(16, 16, 4), 256, 0, stream>>>(Wq, Wk, Wv, Wo,
                                                Wtq, Wtk, Wtv, Wto);
    qkv_gemm<<<dim3(32, 8, 3), 256, 0, stream>>>(Qbf, Kbf, Vbf, Wtq, Wtk, Wtv,
                                                 bq, bk, bv, qw, kw, vtw);
    attn_mfma<<<2048, 256, 0, stream>>>(qw, kw, vtw, opart, lwb);
    attn_combine<<<2048, 256, 0, stream>>>(opart, lwb, attnb);
    out_gemm<<<dim3(32, 16), 256, 0, stream>>>(attnb, Wto, bo, out);
}

// Round 9
// 214.424 us; speedup vs baseline: 1.8605x; 1.8605x over previous
//
#include <hip/hip_runtime.h>
#include <math.h>

#define SEQ   2048
#define DM    1024
#define NH    16
#define DK    64
#define MTOT  4096
// q pre-scale: 1/sqrt(64) * log2(e), so softmax runs in exp2 domain
#define QSCALE 0.18033688011112043f

typedef __bf16 bf16x8 __attribute__((ext_vector_type(8)));
typedef float  f32x4  __attribute__((ext_vector_type(4)));
typedef unsigned short u16;
typedef unsigned long long u64;

// RNE float->bf16 (finite inputs)
__device__ __forceinline__ u16 f2bf(float f) {
    unsigned int u = __float_as_uint(f);
    u += 0x7fff + ((u >> 16) & 1);
    return (u16)(u >> 16);
}

// async global->LDS, 16B per lane; LDS dest = base + lane*16 (HW semantics)
__device__ __forceinline__ void async16(const void* g, void* l) {
    __builtin_amdgcn_global_load_lds(
        (const __attribute__((address_space(1))) unsigned int*)(unsigned long long)g,
        (__attribute__((address_space(3))) unsigned int*)(unsigned int)(unsigned long long)l,
        16, 0, 0);
}

// Alias-safe accessors (memcpy => universal aliasing; same ds codegen)
__device__ __forceinline__ bf16x8 ld16(const u16* p) {        // 16B aligned
    bf16x8 v;
    __builtin_memcpy(&v, p, 16);
    return v;
}
__device__ __forceinline__ void st8(u16* p, unsigned int lo, unsigned int hi) {
    u64 q = ((u64)hi << 32) | lo;
    __builtin_memcpy(p, &q, 8);
}

// ---------------------------------------------------------------------------
// fp32 -> bf16 elementwise (Q, K, V inputs), 8 elems/thread
// ---------------------------------------------------------------------------
__global__ __launch_bounds__(256)
void cvt_in(const float* __restrict__ Q, const float* __restrict__ K,
            const float* __restrict__ V, u16* __restrict__ Qb,
            u16* __restrict__ Kb, u16* __restrict__ Vb)
{
    const float* src; u16* dst;
    if (blockIdx.z == 0)      { src = Q; dst = Qb; }
    else if (blockIdx.z == 1) { src = K; dst = Kb; }
    else                      { src = V; dst = Vb; }
    const size_t i = ((size_t)blockIdx.x * 256 + threadIdx.x) * 8;
    float4 a = *(const float4*)&src[i];
    float4 b = *(const float4*)&src[i + 4];
    uint4 o;
    o.x = (unsigned)f2bf(a.x) | ((unsigned)f2bf(a.y) << 16);
    o.y = (unsigned)f2bf(a.z) | ((unsigned)f2bf(a.w) << 16);
    o.z = (unsigned)f2bf(b.x) | ((unsigned)f2bf(b.y) << 16);
    o.w = (unsigned)f2bf(b.z) | ((unsigned)f2bf(b.w) << 16);
    *(uint4*)&dst[i] = o;
}

// ---------------------------------------------------------------------------
// W [k][n] fp32 -> Wt [n][k] bf16 (64x64 tiles via LDS)
// ---------------------------------------------------------------------------
__global__ __launch_bounds__(256)
void cvt_wt(const float* __restrict__ Wq, const float* __restrict__ Wk,
            const float* __restrict__ Wv, const float* __restrict__ Wo,
            u16* __restrict__ Tq, u16* __restrict__ Tk,
            u16* __restrict__ Tv, u16* __restrict__ To)
{
    const float* W; u16* Wt;
    if (blockIdx.z == 0)      { W = Wq; Wt = Tq; }
    else if (blockIdx.z == 1) { W = Wk; Wt = Tk; }
    else if (blockIdx.z == 2) { W = Wv; Wt = Tv; }
    else                      { W = Wo; Wt = To; }
    __shared__ float Ts[64][65];
    const int t = threadIdx.x;
    const int k0 = blockIdx.x * 64, n0 = blockIdx.y * 64;
#pragma unroll
    for (int p = 0; p < 4; ++p) {
        const int flat = t + p * 256;
        const int r = flat >> 4, c4 = (flat & 15) * 4;
        float4 v = *(const float4*)&W[(size_t)(k0 + r) * DM + n0 + c4];
        Ts[r][c4 + 0] = v.x; Ts[r][c4 + 1] = v.y;
        Ts[r][c4 + 2] = v.z; Ts[r][c4 + 3] = v.w;
    }
    __syncthreads();
#pragma unroll
    for (int p = 0; p < 2; ++p) {
        const int flat = t + p * 256;
        const int n = flat >> 3, kc = (flat & 7) * 8;
        uint4 o;
        o.x = (unsigned)f2bf(Ts[kc + 0][n]) | ((unsigned)f2bf(Ts[kc + 1][n]) << 16);
        o.y = (unsigned)f2bf(Ts[kc + 2][n]) | ((unsigned)f2bf(Ts[kc + 3][n]) << 16);
        o.z = (unsigned)f2bf(Ts[kc + 4][n]) | ((unsigned)f2bf(Ts[kc + 5][n]) << 16);
        o.w = (unsigned)f2bf(Ts[kc + 6][n]) | ((unsigned)f2bf(Ts[kc + 7][n]) << 16);
        *(uint4*)&Wt[(size_t)(n0 + n) * DM + k0 + kc] = o;
    }
}

// ---------------------------------------------------------------------------
// bf16 MFMA GEMM (R5-proven m97 structure): C = A * Wt^T + bias
// 128x128 tile, BK=32, 4 waves 2x2, each wave 4x4 of 16x16x32 MFMA.
// SCATTER=1: bf16 out [bh][s][dk] (with scale); SCATTER=2: bf16 out
// [bh][dk][s] (transposed); SCATTER=0: fp32 out [m][n].
// ---------------------------------------------------------------------------
template <int SCATTER>
__device__ __forceinline__ void gemm_core(const u16* __restrict__ A,
                                          const u16* __restrict__ Wt,
                                          const float* __restrict__ bias,
                                          void* __restrict__ Out, float scale)
{
    __shared__ u16 As[128 * 32];
    __shared__ u16 Bs[128 * 32];

    const int tid = threadIdx.x;
    const int lane = tid & 63;
    const int wv = __builtin_amdgcn_readfirstlane(tid >> 6);
    const int wm = wv >> 1, wn = wv & 1;
    const int lane15 = lane & 15, quad = lane >> 4;
    const int row0 = blockIdx.x * 128, col0 = blockIdx.y * 128;

    const int arow = lane >> 2;          // 0..15
    const int acol = (lane & 3) * 8;     // bf16 col within 32

    f32x4 acc[4][4];
#pragma unroll
    for (int i = 0; i < 4; ++i)
#pragma unroll
        for (int j = 0; j < 4; ++j) acc[i][j] = (f32x4)0.f;

    for (int k0 = 0; k0 < DM; k0 += 32) {
#pragma unroll
        for (int cc = 0; cc < 2; ++cc) {
            const int c = 2 * wv + cc;
            async16(&A[(size_t)(row0 + c * 16 + arow) * DM + k0 + acol],
                    &As[c * 512]);
            async16(&Wt[(size_t)(col0 + c * 16 + arow) * DM + k0 + acol],
                    &Bs[c * 512]);
        }
        __syncthreads();

        bf16x8 af[4];
#pragma unroll
        for (int mi = 0; mi < 4; ++mi)
            af[mi] = ld16(&As[(wm * 64 + mi * 16 + lane15) * 32 + quad * 8]);
#pragma unroll
        for (int ni = 0; ni < 4; ++ni) {
            bf16x8 bfrag = ld16(&Bs[(wn * 64 + ni * 16 + lane15) * 32 + quad * 8]);
#pragma unroll
            for (int mi = 0; mi < 4; ++mi)
                acc[mi][ni] = __builtin_amdgcn_mfma_f32_16x16x32_bf16(
                    af[mi], bfrag, acc[mi][ni], 0, 0, 0);
        }
        __syncthreads();
    }

#pragma unroll
    for (int mi = 0; mi < 4; ++mi) {
        const int mbase = row0 + wm * 64 + mi * 16 + quad * 4;
#pragma unroll
        for (int ni = 0; ni < 4; ++ni) {
            const int n = col0 + wn * 64 + ni * 16 + lane15;
            const float bz = bias[n];
            if (SCATTER == 1) {
                const int h = n >> 6, dk = n & 63;
#pragma unroll
                for (int r = 0; r < 4; ++r) {
                    const int mm = mbase + r;
                    const int b_ = mm >> 11, s = mm & 2047;
                    ((u16*)Out)[(((size_t)(b_ * NH + h)) * SEQ + s) * DK + dk] =
                        f2bf((acc[mi][ni][r] + bz) * scale);
                }
            } else if (SCATTER == 2) {
                const int h = n >> 6, dk = n & 63;
                const int b_ = mbase >> 11, s0 = mbase & 2047;
                u64 q = (u64)f2bf((acc[mi][ni][0] + bz) * scale)
                      | ((u64)f2bf((acc[mi][ni][1] + bz) * scale) << 16)
                      | ((u64)f2bf((acc[mi][ni][2] + bz) * scale) << 32)
                      | ((u64)f2bf((acc[mi][ni][3] + bz) * scale) << 48);
                u16* dst = (u16*)Out +
                    (((size_t)(b_ * NH + h)) * DK + dk) * SEQ + s0;
                __builtin_memcpy(dst, &q, 8);
            } else {
#pragma unroll
                for (int r = 0; r < 4; ++r) {
                    const int mm = mbase + r;
                    ((float*)Out)[(size_t)mm * DM + n] = acc[mi][ni][r] + bz;
                }
            }
        }
    }
}

__global__ __launch_bounds__(256)
void qkv_gemm(const u16* __restrict__ Qb, const u16* __restrict__ Kb,
              const u16* __restrict__ Vb,
              const u16* __restrict__ Tq, const u16* __restrict__ Tk,
              const u16* __restrict__ Tv,
              const float* __restrict__ bq, const float* __restrict__ bk,
              const float* __restrict__ bv,
              u16* __restrict__ qw, u16* __restrict__ kw, u16* __restrict__ vtw)
{
    if (blockIdx.z == 0)      gemm_core<1>(Qb, Tq, bq, qw, QSCALE);
    else if (blockIdx.z == 1) gemm_core<1>(Kb, Tk, bk, kw, 1.0f);
    else                      gemm_core<2>(Vb, Tv, bv, vtw, 1.0f);
}

// ---------------------------------------------------------------------------
// Output GEMM: 128x64 tiles, BK=32 (R5-proven). 512 blocks (2/CU).
// ---------------------------------------------------------------------------
__global__ __launch_bounds__(256)
void out_gemm(const u16* __restrict__ A, const u16* __restrict__ Wt,
              const float* __restrict__ bias, float* __restrict__ Out)
{
    __shared__ u16 As[128 * 32];
    __shared__ u16 Bs[64 * 32];

    const int tid = threadIdx.x;
    const int lane = tid & 63;
    const int wv = __builtin_amdgcn_readfirstlane(tid >> 6);
    const int wm = wv >> 1, wn = wv & 1;
    const int lane15 = lane & 15, quad = lane >> 4;
    const int row0 = blockIdx.x * 128, col0 = blockIdx.y * 64;

    const int arow = lane >> 2;
    const int acol = (lane & 3) * 8;

    f32x4 acc[4][2];
#pragma unroll
    for (int i = 0; i < 4; ++i)
#pragma unroll
        for (int j = 0; j < 2; ++j) acc[i][j] = (f32x4)0.f;

    for (int k0 = 0; k0 < DM; k0 += 32) {
#pragma unroll
        for (int cc = 0; cc < 2; ++cc) {
            const int c = 2 * wv + cc;
            async16(&A[(size_t)(row0 + c * 16 + arow) * DM + k0 + acol],
                    &As[c * 512]);
        }
        async16(&Wt[(size_t)(col0 + wv * 16 + arow) * DM + k0 + acol],
                &Bs[wv * 512]);
        __syncthreads();

        bf16x8 af[4];
#pragma unroll
        for (int mi = 0; mi < 4; ++mi)
            af[mi] = ld16(&As[(wm * 64 + mi * 16 + lane15) * 32 + quad * 8]);
#pragma unroll
        for (int ni = 0; ni < 2; ++ni) {
            bf16x8 bfrag = ld16(&Bs[(wn * 32 + ni * 16 + lane15) * 32 + quad * 8]);
#pragma unroll
            for (int mi = 0; mi < 4; ++mi)
                acc[mi][ni] = __builtin_amdgcn_mfma_f32_16x16x32_bf16(
                    af[mi], bfrag, acc[mi][ni], 0, 0, 0);
        }
        __syncthreads();
    }

#pragma unroll
    for (int mi = 0; mi < 4; ++mi) {
        const int mbase = row0 + wm * 64 + mi * 16 + quad * 4;
#pragma unroll
        for (int ni = 0; ni < 2; ++ni) {
            const int n = col0 + wn * 32 + ni * 16 + lane15;
            const float bz = bias[n];
#pragma unroll
            for (int r = 0; r < 4; ++r)
                Out[(size_t)(mbase + r) * DM + n] = acc[mi][ni][r] + bz;
        }
    }
}

// ---------------------------------------------------------------------------
// Flash attention, bf16 MFMA, linear softmax, split-K over key halves.
// KEY TRICK: compute S^T = K*Q^T (operands swapped). C-layout then holds,
// per lane, P[q = mi*16 + lane15][key = 16*ki + 4*quad + r]. With the key
// permutation sigma(kk,quad,j) = 16*(2kk+(j>>2)) + 4*quad + (j&3), that set
// equals exactly the keys the lane's PV A-fragment must supply -> P is
// repacked IN-REGISTER into PV A-fragments, no LDS roundtrip, no cross-lane.
// V is staged into LDS with sigma's slot order. O in standard C-layout.
// Double-buffered K/V tiles -> ONE barrier per tile.
// R9 (softmax thinning): (a) l accumulated via MFMA against a ones B-matrix
// (4 extra MFMA/tile replace 32 v_add_f32 + epilogue shuffles; l now exactly
// consistent with the rounded-bf16 P that PV consumes); (b) P->bf16 packing
// via direct RNE casts into bf16x8 (compiler emits v_cvt_pk_bf16_f32),
// replacing the add+perm bit-trick. [R8 5-blocks/CU attempt REVERTED:
// launch_bounds(256,5) forced VGPR 48 -> scratch spills -> 1 GB HBM/dispatch,
// 221 us. Occupancy >16 waves/CU needs <=64 VGPR: closed for this kernel.]
// R7: 4 waves x 32 q-rows sharing one K/V tile, 16 waves/CU.
// R6: s_setprio(1) around MFMA clusters.
// ---------------------------------------------------------------------------
__global__ __launch_bounds__(256, 4)
void attn_mfma(const u16* __restrict__ qw, const u16* __restrict__ kw,
               const u16* __restrict__ vt, u16* __restrict__ opart,
               float* __restrict__ lw)
{
    __shared__ u16 Ks[2][64 * 72];    // [key][d], natural, stride 72 (16B rows)
    __shared__ u16 Vts[2][64 * 72];   // [dv][key-slot], sigma order

    const int tid = threadIdx.x;
    const int lane = tid & 63;
    const int wv = tid >> 6;                 // 0..3
    const int lane15 = lane & 15, quad = lane >> 4;

    // bf16 ones vector for the l-accumulating MFMA (1.0bf16 = 0x3F80)
    union { unsigned int u[4]; bf16x8 v; } ones_u;
#pragma unroll
    for (int j = 0; j < 4; ++j) ones_u.u[j] = 0x3F803F80u;
    const bf16x8 kOnes = ones_u.v;

    // XCD-swizzled decode: 4 heads per XCD (2 MB K/V resident in L2)
    const int flat = blockIdx.x;             // 0..1023
    const int xcd = flat & 7;
    const int rest = flat >> 3;              // 0..127
    const int bh = xcd * 4 + (rest & 3);     // 0..31
    const int qt = (rest >> 2) & 15;         // 0..15
    const int ks = rest >> 6;                // key half 0/1
    const int q0 = qt * 128;
    const int c0beg = ks * 1024;
    const size_t base = (size_t)bh * SEQ * DK;

    // Q fragments (B-operand of S^T): wave rows = q0 + wv*32 + mi*16 + lane15
    bf16x8 qb[2][2];
#pragma unroll
    for (int mi = 0; mi < 2; ++mi)
#pragma unroll
        for (int kk = 0; kk < 2; ++kk)
            qb[mi][kk] = ld16(&qw[base +
                (size_t)(q0 + wv * 32 + mi * 16 + lane15) * DK + kk * 32 + quad * 8]);

    f32x4 o_acc[2][4];
    f32x4 l_acc[2];
#pragma unroll
    for (int mi = 0; mi < 2; ++mi) {
        l_acc[mi] = (f32x4)0.f;
#pragma unroll
        for (int nd = 0; nd < 4; ++nd) o_acc[mi][nd] = (f32x4)0.f;
    }

    // staging map: 256 thr cover 64 rows x 64 cols (four 16-col quarters)
    const int sr = tid >> 2;                 // 0..63
    const int sh = (tid & 3) * 16;           // col quarter base

    // V slot bases for the 2 col-groups (sigma-contiguous 4-key runs)
    int vslot[2];
#pragma unroll
    for (int j = 0; j < 2; ++j) {
        const int c8 = sh + j * 8;
        const int a = c8 >> 4, b = (c8 >> 2) & 3;
        vslot[j] = (a >> 1) * 32 + b * 8 + (a & 1) * 4;
    }

    // stage tile 0 into buffer 0
#pragma unroll
    for (int j = 0; j < 2; ++j) {
        const int c8 = sh + j * 8;
        uint4 kv = *(const uint4*)&kw[base + (size_t)(c0beg + sr) * DK + c8];
        st8(&Ks[0][sr * 72 + c8], kv.x, kv.y);
        st8(&Ks[0][sr * 72 + c8 + 4], kv.z, kv.w);
        uint4 vv = *(const uint4*)&vt[base + (size_t)sr * SEQ + c0beg + c8];
        st8(&Vts[0][sr * 72 + vslot[j]], vv.x, vv.y);
        st8(&Vts[0][sr * 72 + vslot[j] + 8], vv.z, vv.w);
    }
    __syncthreads();

    for (int it = 0; it < 16; ++it) {
        const int cur = it & 1;
        const u16* Kc = &Ks[cur][0];
        const u16* Vc = &Vts[cur][0];

        // prefetch next tile into registers
        uint4 kpre[2], vpre[2];
        const bool more = (it < 15);
        if (more) {
            const int cn = c0beg + (it + 1) * 64;
#pragma unroll
            for (int j = 0; j < 2; ++j) {
                const int c8 = sh + j * 8;
                kpre[j] = *(const uint4*)&kw[base + (size_t)(cn + sr) * DK + c8];
                vpre[j] = *(const uint4*)&vt[base + (size_t)sr * SEQ + cn + c8];
            }
        }

        // S^T = K * Q^T : rows = keys (ki), cols = q
        f32x4 sT[2][4];
#pragma unroll
        for (int mi = 0; mi < 2; ++mi)
#pragma unroll
            for (int ki = 0; ki < 4; ++ki) sT[mi][ki] = (f32x4)0.f;
        __builtin_amdgcn_s_setprio(1);
#pragma unroll
        for (int ki = 0; ki < 4; ++ki)
#pragma unroll
            for (int kk = 0; kk < 2; ++kk) {
                bf16x8 ka = ld16(&Kc[(ki * 16 + lane15) * 72 + kk * 32 + quad * 8]);
#pragma unroll
                for (int mi = 0; mi < 2; ++mi)
                    sT[mi][ki] = __builtin_amdgcn_mfma_f32_16x16x32_bf16(
                        ka, qb[mi][kk], sT[mi][ki], 0, 0, 0);
            }
        __builtin_amdgcn_s_setprio(0);

        // softmax: p = exp2(sT) in place (pre-scaled scores)
#pragma unroll
        for (int mi = 0; mi < 2; ++mi)
#pragma unroll
            for (int ki = 0; ki < 4; ++ki)
#pragma unroll
                for (int r = 0; r < 4; ++r)
                    sT[mi][ki][r] = __builtin_amdgcn_exp2f(sT[mi][ki][r]);

        // pack P to PV A-fragments via RNE casts (compiler: v_cvt_pk_bf16_f32)
        // pa[mi][kk][e] = bf16(P[ki = 2kk + (e>>2)][r = e&3])
        bf16x8 pa[2][2];
#pragma unroll
        for (int mi = 0; mi < 2; ++mi)
#pragma unroll
            for (int kk = 0; kk < 2; ++kk) {
                bf16x8 t;
#pragma unroll
                for (int e = 0; e < 8; ++e)
                    t[e] = (__bf16)sT[mi][2 * kk + (e >> 2)][e & 3];
                pa[mi][kk] = t;
            }

        // PV: O += P * V ; l += P * ones (sigma slot order matches k-slots)
        __builtin_amdgcn_s_setprio(1);
#pragma unroll
        for (int kk = 0; kk < 2; ++kk) {
#pragma unroll
            for (int mi = 0; mi < 2; ++mi)
                l_acc[mi] = __builtin_amdgcn_mfma_f32_16x16x32_bf16(
                    pa[mi][kk], kOnes, l_acc[mi], 0, 0, 0);
#pragma unroll
            for (int nd = 0; nd < 4; ++nd) {
                bf16x8 vb = ld16(&Vc[(nd * 16 + lane15) * 72 + kk * 32 + quad * 8]);
#pragma unroll
                for (int mi = 0; mi < 2; ++mi)
                    o_acc[mi][nd] = __builtin_amdgcn_mfma_f32_16x16x32_bf16(
                        pa[mi][kk], vb, o_acc[mi][nd], 0, 0, 0);
            }
        }
        __builtin_amdgcn_s_setprio(0);

        // write prefetched tile into the other buffer (its readers finished
        // at the previous barrier), then one barrier to publish + retire cur
        if (more) {
            const int nxt = cur ^ 1;
#pragma unroll
            for (int j = 0; j < 2; ++j) {
                const int c8 = sh + j * 8;
                st8(&Ks[nxt][sr * 72 + c8], kpre[j].x, kpre[j].y);
                st8(&Ks[nxt][sr * 72 + c8 + 4], kpre[j].z, kpre[j].w);
                st8(&Vts[nxt][sr * 72 + vslot[j]], vpre[j].x, vpre[j].y);
                st8(&Vts[nxt][sr * 72 + vslot[j] + 8], vpre[j].z, vpre[j].w);
            }
        }
        __syncthreads();
    }

    // epilogue: l_acc C-layout = o_acc layout: q = mi*16 + quad*4 + r, all
    // lane15 columns hold the same row-sum -> write from lane15 == 0 only.
    const size_t rowbase = (size_t)(ks * 32 + bh) * SEQ;
    if (lane15 == 0) {
#pragma unroll
        for (int mi = 0; mi < 2; ++mi)
#pragma unroll
            for (int r = 0; r < 4; ++r)
                lw[rowbase + q0 + wv * 32 + mi * 16 + quad * 4 + r] =
                    l_acc[mi][r];
    }
    // unnormalized partial O: q = mi*16 + quad*4 + r, dv = nd*16 + lane15
#pragma unroll
    for (int mi = 0; mi < 2; ++mi)
#pragma unroll
        for (int r = 0; r < 4; ++r) {
            const int s = q0 + wv * 32 + mi * 16 + quad * 4 + r;
#pragma unroll
            for (int nd = 0; nd < 4; ++nd)
                opart[(rowbase + s) * DK + nd * 16 + lane15] = f2bf(o_acc[mi][nd][r]);
        }
}

// ---------------------------------------------------------------------------
// Combine the two key-half partials: O = (O0 + O1) / (l0 + l1), bf16 out.
// ---------------------------------------------------------------------------
__global__ __launch_bounds__(256)
void attn_combine(const u16* __restrict__ opart, const float* __restrict__ lw,
                  u16* __restrict__ attnb)
{
    const int flat = blockIdx.x * 256 + threadIdx.x;   // < 524288
    const int dv = (flat & 7) * 8;
    const int s  = (flat >> 3) & 2047;
    const int bh = flat >> 14;
    const size_t i0 = ((size_t)bh * SEQ + s) * DK + dv;
    const size_t i1 = i0 + (size_t)32 * SEQ * DK;
    uint4 a = *(const uint4*)&opart[i0];
    uint4 b = *(const uint4*)&opart[i1];
    const float l = lw[(size_t)bh * SEQ + s] + lw[(size_t)(32 + bh) * SEQ + s];
    const float inv = 1.f / l;
    unsigned int au[4] = {a.x, a.y, a.z, a.w};
    unsigned int bu[4] = {b.x, b.y, b.z, b.w};
    unsigned int ou[4];
#pragma unroll
    for (int j = 0; j < 4; ++j) {
        const float e0 = __uint_as_float(au[j] << 16) + __uint_as_float(bu[j] << 16);
        const float e1 = __uint_as_float(au[j] & 0xffff0000u) +
                         __uint_as_float(bu[j] & 0xffff0000u);
        ou[j] = (unsigned)f2bf(e0 * inv) | ((unsigned)f2bf(e1 * inv) << 16);
    }
    const int b_ = bh >> 4, h = bh & 15;
    uint4 o; o.x = ou[0]; o.y = ou[1]; o.z = ou[2]; o.w = ou[3];
    *(uint4*)&attnb[((size_t)b_ * SEQ + s) * DM + h * DK + dv] = o;
}

// ---------------------------------------------------------------------------
extern "C" void kernel_launch(void* const* d_in, const int* in_sizes, int n_in,
                              void* d_out, int out_size, void* d_ws, size_t ws_size,
                              hipStream_t stream)
{
    const float* Q  = (const float*)d_in[0];
    const float* K  = (const float*)d_in[1];
    const float* V  = (const float*)d_in[2];
    const float* Wq = (const float*)d_in[3];
    const float* bq = (const float*)d_in[4];
    const float* Wk = (const float*)d_in[5];
    const float* bk = (const float*)d_in[6];
    const float* Wv = (const float*)d_in[7];
    const float* bv = (const float*)d_in[8];
    const float* Wo = (const float*)d_in[9];
    const float* bo = (const float*)d_in[10];
    float* out = (float*)d_out;

    const size_t MB = 1024 * 1024;
    char* w8 = (char*)d_ws;
    u16* Qbf = (u16*)(w8 + 0 * MB);      // 8 MB (aliased as attn out later)
    u16* Kbf = (u16*)(w8 + 8 * MB);      // dead after qkv -> opart
    u16* Vbf = (u16*)(w8 + 16 * MB);     // dead after qkv -> opart
    u16* Wtq = (u16*)(w8 + 24 * MB);     // 2 MB each
    u16* Wtk = (u16*)(w8 + 26 * MB);
    u16* Wtv = (u16*)(w8 + 28 * MB);
    u16* Wto = (u16*)(w8 + 30 * MB);     // alive until out_gemm
    u16* qw  = (u16*)(w8 + 32 * MB);     // 8 MB [bh][s][dk]
    u16* kw  = (u16*)(w8 + 40 * MB);     // 8 MB [bh][s][dk]
    u16* vtw = (u16*)(w8 + 48 * MB);     // 8 MB [bh][dk][s] (direct from qkv)
    u16* opart = Kbf;                    // 16 MB @ 8..24: partial O (bf16)
    float* lwb = (float*)(w8 + 56 * MB); // 512 KB: partial l (fp32)
    u16* attnb = Qbf;                    // alias: Qbf dead after qkv_gemm

    cvt_in<<<dim3(2048, 1, 3), 256, 0, stream>>>(Q, K, V, Qbf, Kbf, Vbf);
    cvt_wt<<<dim3(16, 16, 4), 256, 0, stream>>>(Wq, Wk, Wv, Wo,
                                                Wtq, Wtk, Wtv, Wto);
    qkv_gemm<<<dim3(32, 8, 3), 256, 0, stream>>>(Qbf, Kbf, Vbf, Wtq, Wtk, Wtv,
                                                 bq, bk, bv, qw, kw, vtw);
    attn_mfma<<<1024, 256, 0, stream>>>(qw, kw, vtw, opart, lwb);
    attn_combine<<<2048, 256, 0, stream>>>(opart, lwb, attnb);
    out_gemm<<<dim3(32, 16), 256, 0, stream>>>(attnb, Wto, bo, out);
}